// Round 15
// baseline (135.229 us; speedup 1.0000x reference)
//
#include <hip/hip_runtime.h>
#include <hip/hip_bf16.h>
#include <hip/hip_fp16.h>
#include <cstdint>
#include <cstddef>

#define L_TOT 16384
#define B_SZ 2
#define NROW (B_SZ * L_TOT)
#define CHUNK 32
#define NCH (L_TOT / CHUNK)      // 512

static constexpr size_t SLOT_XD  = (size_t)NROW * 64;           // fp32 slots (xbuf/zbuf)
static constexpr size_t HSLOT_XD = (size_t)NROW * 64;           // xd (u), fp16, per dir
static constexpr size_t HSLOT_BC = (size_t)NROW * 16;           // B(8)+C(8), fp16, per dir
static constexpr size_t HSLOT_DT = (size_t)NROW * 64;           // dt (post-softplus), fp16
static constexpr size_t SLOT_SDT = (size_t)B_SZ * 64 * NCH;     // sum(dt), [b][d][ch], fp16
static constexpr size_t SLOT_HC  = (size_t)B_SZ * NCH * 64 * 8; // chunk h, [b][ch][d][n], fp16

union H8pack { float4 f4; __half2 h2[4]; };
union H4pack { float2 f2; __half2 h2[2]; };

typedef _Float16 h2v __attribute__((ext_vector_type(2)));
#if __has_builtin(__builtin_amdgcn_fdot2)
#define FDOT2(a, b, c) __builtin_amdgcn_fdot2((a), (b), (c), false)
#else
#define FDOT2(a, b, c) fmaf((float)(a)[0], (float)(b)[0], fmaf((float)(a)[1], (float)(b)[1], (c)))
#endif

// scan-position s -> original sequence index l (involution; verified rounds 1-2).
__device__ __forceinline__ int tau_map(int dir, int s) {
  int j = (dir & 1) ? (L_TOT - 1 - s) : s;
  if (dir >= 2) j = ((j & 127) << 7) | (j >> 7);   // transpose of 128x128
  return j;
}
__device__ __forceinline__ float silu_f(float x) { return x / (1.f + __expf(-x)); }
__device__ __forceinline__ float softplus_f(float x) {
  return fmaxf(x, 0.f) + __logf(1.f + __expf(-fabsf(x)));
}

// ---- A: LN + in_proj as LDS-tiled GEMM. 256 thr, 4x8 register sub-tile per thread. ----
__global__ void __launch_bounds__(256)
k_ln_inproj(const float* __restrict__ inp, const float* __restrict__ lng,
            const float* __restrict__ lnb, const float* __restrict__ W,
            float* __restrict__ xout, float* __restrict__ zout) {
  __shared__ float xt[64 * 65];        // input tile [l][c], pad 65 (conflict-free)
  __shared__ float wrk[8448];          // stats(640) -> W[128][65] -> so[64][132]
  const int t = threadIdx.x;
  const int lane = t & 63;
  const int w = t >> 6;
  const int b = blockIdx.x >> 8;
  const int l0 = (blockIdx.x & 255) << 6;
  const float* ip = inp + (size_t)b * 64 * L_TOT + l0 + lane;
#pragma unroll 4
  for (int cc = 0; cc < 16; ++cc) {
    int c = cc * 4 + w;
    xt[lane * 65 + c] = ip[(size_t)c * L_TOT];
  }
  __syncthreads();
  {
    float s1 = 0.f, s2 = 0.f;
    const int c0 = w * 16;
#pragma unroll
    for (int cc = 0; cc < 16; ++cc) {
      float v = xt[lane * 65 + c0 + cc];
      s1 += v; s2 = fmaf(v, v, s2);
    }
    wrk[w * 64 + lane] = s1;
    wrk[256 + w * 64 + lane] = s2;
  }
  __syncthreads();
  if (t < 64) {
    float s1 = wrk[t] + wrk[64 + t] + wrk[128 + t] + wrk[192 + t];
    float s2 = wrk[256 + t] + wrk[320 + t] + wrk[384 + t] + wrk[448 + t];
    float m = s1 * 0.015625f;
    float var = s2 * 0.015625f - m * m;
    wrk[512 + t] = m;
    wrk[576 + t] = rsqrtf(var + 1e-5f);
  }
  __syncthreads();
  {
    const float mv = wrk[512 + lane], rv = wrk[576 + lane];
#pragma unroll 4
    for (int k = 0; k < 16; ++k) {
      int c = w + 4 * k;
      float g = lng[c], bb = lnb[c];
      float v = xt[lane * 65 + c];
      xt[lane * 65 + c] = (v - mv) * rv * g + bb;
    }
  }
  __syncthreads();
#pragma unroll 4
  for (int rep = 0; rep < 32; ++rep) {
    int j = rep * 4 + w;
    wrk[j * 65 + lane] = W[(size_t)j * 64 + lane];
  }
  __syncthreads();
  const int rg = lane & 15;
  const int jg = lane >> 4;
  const int j0 = w * 32 + jg * 8;
  const int r0 = rg * 4;
  float acc[4][8] = {};
#pragma unroll 2
  for (int c = 0; c < 64; ++c) {
    float xv[4], wv[8];
#pragma unroll
    for (int i = 0; i < 4; ++i) xv[i] = xt[(r0 + i) * 65 + c];
#pragma unroll
    for (int jj = 0; jj < 8; ++jj) wv[jj] = wrk[(j0 + jj) * 65 + c];
#pragma unroll
    for (int i = 0; i < 4; ++i)
#pragma unroll
      for (int jj = 0; jj < 8; ++jj) acc[i][jj] = fmaf(xv[i], wv[jj], acc[i][jj]);
  }
  __syncthreads();
#pragma unroll
  for (int i = 0; i < 4; ++i)
#pragma unroll
    for (int jj = 0; jj < 8; ++jj) wrk[(r0 + i) * 132 + j0 + jj] = acc[i][jj];
  __syncthreads();
  float* xo = xout + ((size_t)b * L_TOT + l0) * 64;
  float* zo = zout + ((size_t)b * L_TOT + l0) * 64;
#pragma unroll 4
  for (int rep = 0; rep < 16; ++rep) {
    int r = rep * 4 + w;
    xo[(size_t)r * 64 + lane] = wrk[r * 132 + lane];
    zo[(size_t)r * 64 + lane] = wrk[r * 132 + 64 + lane];
  }
}

// ---- B: gather + conv(4) + SiLU + xproj(dot2) + dt precompute + fused scan1 ----
// (round-13 version: proven 46.5us; dt stored fp16 to global, reloaded by tail via L2)
__global__ void __launch_bounds__(256)
k_convscan(const float* __restrict__ xbuf, const float* __restrict__ cw,
           const float* __restrict__ cb, const float* __restrict__ xpw,
           const float* __restrict__ dtw, const float* __restrict__ dtbias,
           const float* __restrict__ alog,
           __half* __restrict__ xd_base, __half* __restrict__ bc_base,
           __half* __restrict__ dtb_base,
           __half* __restrict__ hcb, __half* __restrict__ sdtb, int dir_base) {
  __shared__ __align__(16) _Float16 xh[67 * 70];   // halo'd x tile -> u tile, fp16
  __shared__ __align__(16) _Float16 wt[20 * 70];   // xproj weights, fp16
  __shared__ __align__(16) float dbl[64 * 20];     // dtr+B+C rows, fp32
  const int t = threadIdx.x;
  const int lane = t & 63;
  const int w = t >> 6;
  const int slot = blockIdx.y;
  const int dir = dir_base + slot;
  const int blk = blockIdx.x;
  const int b = blk >> 8;
  const int s0 = (blk & 255) << 6;
  const float* xb = xbuf + (size_t)b * L_TOT * 64;
#pragma unroll 1
  for (int i = w; i < 67; i += 4) {
    int s = s0 - 3 + i;
    float v = 0.f;
    if (s >= 0) v = xb[(size_t)tau_map(dir, s) * 64 + lane];
    xh[i * 70 + lane] = (_Float16)v;
  }
#pragma unroll
  for (int jj = 0; jj < 5; ++jj) {
    int j = jj * 4 + w;
    wt[j * 70 + lane] = (_Float16)xpw[((size_t)dir * 20 + j) * 64 + lane];
  }
  __syncthreads();
  float wk[4];
#pragma unroll
  for (int k = 0; k < 4; ++k) wk[k] = cw[(dir * 64 + lane) * 4 + k];
  const float bconv = cb[dir * 64 + lane];
  float u[16];
  __half* xdp = xd_base + (size_t)slot * HSLOT_XD + ((size_t)b * L_TOT + s0) * 64;
#pragma unroll 4
  for (int rr = 0; rr < 16; ++rr) {
    const int r = rr * 4 + w;
    float acc = bconv;
#pragma unroll
    for (int k = 0; k < 4; ++k) acc = fmaf(wk[k], (float)xh[(r + k) * 70 + lane], acc);
    acc = silu_f(acc);
    u[rr] = acc;
    xdp[(size_t)r * 64 + lane] = __float2half(acc);
  }
  __syncthreads();   // conv reads of xh complete
#pragma unroll 4
  for (int rr = 0; rr < 16; ++rr) xh[(rr * 4 + w) * 70 + lane] = (_Float16)u[rr];
  __syncthreads();
  {  // xproj: wave w computes j = 5w..5w+4 for all 64 rows (row = lane), half2 dot2
    float acc5[5] = {0.f, 0.f, 0.f, 0.f, 0.f};
    const _Float16* xr = xh + lane * 70;
#pragma unroll 4
    for (int c2 = 0; c2 < 32; ++c2) {
      h2v xv = *(const h2v*)(xr + 2 * c2);
#pragma unroll
      for (int jj = 0; jj < 5; ++jj) {
        h2v wv = *(const h2v*)(wt + (w * 5 + jj) * 70 + 2 * c2);
        acc5[jj] = FDOT2(xv, wv, acc5[jj]);
      }
    }
#pragma unroll
    for (int jj = 0; jj < 5; ++jj) dbl[lane * 20 + w * 5 + jj] = acc5[jj];
  }
  __syncthreads();   // dbl complete (also fences xh u-tile)
  // bc store (B,C only, fp16)
  {
    __half* bcp = bc_base + (size_t)slot * HSLOT_BC + ((size_t)b * L_TOT + s0) * 16;
#pragma unroll
    for (int i = t; i < 1024; i += 256) {
      int r = i >> 4, j = i & 15;
      bcp[i] = __float2half(dbl[r * 20 + 4 + j]);
    }
  }
  // dt precompute: thread (lane=channel) does rows rr*4+w; fp16 to global
  __half* dtp = dtb_base + (size_t)slot * HSLOT_DT + ((size_t)b * L_TOT + s0) * 64;
  {
    float wdt[4];
#pragma unroll
    for (int r = 0; r < 4; ++r) wdt[r] = dtw[((size_t)dir * 64 + lane) * 4 + r];
    const float bia = dtbias[dir * 64 + lane];
#pragma unroll 4
    for (int rr = 0; rr < 16; ++rr) {
      const int r = rr * 4 + w;
      float dt = bia;
#pragma unroll
      for (int q = 0; q < 4; ++q) dt = fmaf(dbl[r * 20 + q], wdt[q], dt);
      dtp[(size_t)r * 64 + lane] = __float2half(softplus_f(dt));
    }
  }
  __syncthreads();   // dt writes drained -> L2-visible
  // ---- fused scan1: wave w scans chunk (w&1), states ng..ng+3; dt from global ----
  {
    const int w2 = w & 1;
    const int ng = (w >> 1) << 2;          // 0 or 4
    const int d = lane;
    const int ch = (s0 >> 5) + w2;
    const float* asrc = alog + ((size_t)dir * 64 + d) * 8;
    float a4[4];
#pragma unroll
    for (int k = 0; k < 4; ++k) a4[k] = -__expf(asrc[ng + k]);
    const float a0 = (ng == 0) ? a4[0] : -__expf(asrc[0]);
    bool pw = true;
#pragma unroll
    for (int k = 0; k < 4; ++k) {
      float tgt = (float)(ng + k + 1) * a0;
      pw = pw && (fabsf(a4[k] - tgt) <= 1e-3f * fabsf(tgt));
    }
    const _Float16* xs = xh + (w2 * 32) * 70;
    const float* ds = dbl + (w2 * 32) * 20;
    const __half* dts = dtp + (size_t)(w2 * 32) * 64;
    float h[4] = {0.f, 0.f, 0.f, 0.f};
    float sdt = 0.f;
    if (pw) {
#pragma unroll 8
      for (int s = 0; s < CHUNK; ++s) {
        float uu = (float)xs[s * 70 + d];
        float dt = __half2float(dts[s * 64 + d]);
        float4 bb = *(const float4*)(ds + s * 20 + 4 + ng);
        sdt += dt;
        float du = dt * uu;
        float p = __expf(dt * a0);
        float p2 = p * p, p4 = p2 * p2;
        float e0, e1, e2, e3;
        if (ng == 0) { e0 = p; e1 = p2; e2 = p2 * p; e3 = p4; }
        else { e0 = p4 * p; e1 = p4 * p2; e2 = e1 * p; e3 = p4 * p4; }
        h[0] = fmaf(e0, h[0], du * bb.x);
        h[1] = fmaf(e1, h[1], du * bb.y);
        h[2] = fmaf(e2, h[2], du * bb.z);
        h[3] = fmaf(e3, h[3], du * bb.w);
      }
    } else {
#pragma unroll 8
      for (int s = 0; s < CHUNK; ++s) {
        float uu = (float)xs[s * 70 + d];
        float dt = __half2float(dts[s * 64 + d]);
        float4 bb = *(const float4*)(ds + s * 20 + 4 + ng);
        sdt += dt;
        float du = dt * uu;
        h[0] = fmaf(__expf(dt * a4[0]), h[0], du * bb.x);
        h[1] = fmaf(__expf(dt * a4[1]), h[1], du * bb.y);
        h[2] = fmaf(__expf(dt * a4[2]), h[2], du * bb.z);
        h[3] = fmaf(__expf(dt * a4[3]), h[3], du * bb.w);
      }
    }
    if (ng == 0)
      sdtb[(size_t)slot * SLOT_SDT + ((size_t)b * 64 + d) * NCH + ch] = __float2half(sdt);
    H4pack pk;
    pk.h2[0] = __floats2half2_rn(h[0], h[1]);
    pk.h2[1] = __floats2half2_rn(h[2], h[3]);
    *(float2*)(hcb + (size_t)slot * SLOT_HC +
               (((size_t)b * NCH + ch) * 64 + d) * 8 + ng) = pk.f2;
  }
}

// ---- S2: parallel chunk stitch (Hillis-Steele over 512 chunks), exclusive in-place ----
__global__ void __launch_bounds__(512)
k_scan2(__half* __restrict__ hcb, const __half* __restrict__ sdtb,
        const float* __restrict__ alog, int dir_base) {
  const int t = threadIdx.x;           // 512 = chunk index
  const int d = blockIdx.x >> 3;
  const int n = blockIdx.x & 7;
  const int slot = blockIdx.y;
  const int dir = dir_base + slot;
  const int b = blockIdx.z;
  const float a = -__expf(alog[((size_t)dir * 64 + d) * 8 + n]);
  __half* hcp = hcb + (size_t)slot * SLOT_HC + (size_t)b * NCH * 512;
  const __half* sdp = sdtb + (size_t)slot * SLOT_SDT + ((size_t)b * 64 + d) * NCH;
  float e = __expf(a * __half2float(sdp[t]));         // coalesced
  float v = __half2float(hcp[((size_t)t * 64 + d) * 8 + n]);
  __shared__ float sE[NCH], sV[NCH];
  sE[t] = e; sV[t] = v;
  __syncthreads();
#pragma unroll
  for (int off = 1; off < NCH; off <<= 1) {
    float pe = 1.f, pv = 0.f;
    if (t >= off) { pe = sE[t - off]; pv = sV[t - off]; }
    __syncthreads();
    v = fmaf(e, pv, v);     // compose: prev then self
    e = e * pe;
    sE[t] = e; sV[t] = v;
    __syncthreads();
  }
  const float hs = (t == 0) ? 0.f : sV[t - 1];   // exclusive = h_start for chunk t
  hcp[((size_t)t * 64 + d) * 8 + n] = __float2half(hs);
}

// ---- S3: final scan; y scatter-added into ysum via non-returning atomics ----
// (fire-and-forget writes replace k_final's blocking 4-dir gather reads)
__global__ void __launch_bounds__(256, 4)
k_scan3(const __half* __restrict__ xd_in, const __half* __restrict__ bc_base,
        const __half* __restrict__ dtb_base, const __half* __restrict__ hcb,
        const float* __restrict__ alog, const float* __restrict__ dsk,
        float* __restrict__ ysum_f, int dir_base) {
  __shared__ __align__(16) float rpl[4 * CHUNK * 16];   // 8 KB (B,C)
  const int t = threadIdx.x;
  const int w = t >> 6;
  const int d = t & 63;
  const int ch = blockIdx.x * 4 + w;
  const int slot = blockIdx.y;
  const int dir = dir_base + slot;
  const int b = blockIdx.z;
  const __half* bcblk = bc_base + (size_t)slot * HSLOT_BC +
                        ((size_t)b * L_TOT + (size_t)blockIdx.x * 4 * CHUNK) * 16;
#pragma unroll
  for (int i = t; i < 4 * CHUNK * 16; i += 256) rpl[i] = __half2float(bcblk[i]);
  __syncthreads();
  const float* rp = rpl + w * CHUNK * 16;
  float a[8];
#pragma unroll
  for (int n = 0; n < 8; ++n) a[n] = -__expf(alog[((size_t)dir * 64 + d) * 8 + n]);
  const float a0 = a[0];
  bool pw = true;
#pragma unroll
  for (int n = 0; n < 8; ++n) {
    float tgt = (float)(n + 1) * a0;
    pw = pw && (fabsf(a[n] - tgt) <= 1e-3f * fabsf(tgt));
  }
  const float Dv = dsk[dir * 64 + d];
  const __half* up  = xd_in + (size_t)slot * HSLOT_XD + ((size_t)b * L_TOT + ch * CHUNK) * 64;
  const __half* dtp = dtb_base + (size_t)slot * HSLOT_DT + ((size_t)b * L_TOT + ch * CHUNK) * 64;
  float h[8];
  {
    H8pack pk;
    pk.f4 = *(const float4*)(hcb + (size_t)slot * SLOT_HC +
                             (((size_t)b * NCH + ch) * 64 + d) * 8);
#pragma unroll
    for (int k = 0; k < 4; ++k) {
      h[2 * k] = __low2float(pk.h2[k]);
      h[2 * k + 1] = __high2float(pk.h2[k]);
    }
  }
  const int sbase = ch * CHUNK;
  if (pw) {
#pragma unroll 8
    for (int s = 0; s < CHUNK; ++s) {
      float u = __half2float(up[s * 64 + d]);
      float dt = __half2float(dtp[s * 64 + d]);
      float4 b0 = *(const float4*)(rp + s * 16);
      float4 b1 = *(const float4*)(rp + s * 16 + 4);
      float4 c0 = *(const float4*)(rp + s * 16 + 8);
      float4 c1 = *(const float4*)(rp + s * 16 + 12);
      float du = dt * u;
      float p = __expf(dt * a0);
      float p2 = p * p, p3 = p2 * p, p4 = p2 * p2;
      float p5 = p4 * p, p6 = p4 * p2, p7 = p4 * p3, p8 = p4 * p4;
      h[0] = fmaf(p,  h[0], du * b0.x);
      h[1] = fmaf(p2, h[1], du * b0.y);
      h[2] = fmaf(p3, h[2], du * b0.z);
      h[3] = fmaf(p4, h[3], du * b0.w);
      h[4] = fmaf(p5, h[4], du * b1.x);
      h[5] = fmaf(p6, h[5], du * b1.y);
      h[6] = fmaf(p7, h[6], du * b1.z);
      h[7] = fmaf(p8, h[7], du * b1.w);
      float y = u * Dv;
      y = fmaf(c0.x, h[0], y); y = fmaf(c0.y, h[1], y);
      y = fmaf(c0.z, h[2], y); y = fmaf(c0.w, h[3], y);
      y = fmaf(c1.x, h[4], y); y = fmaf(c1.y, h[5], y);
      y = fmaf(c1.z, h[6], y); y = fmaf(c1.w, h[7], y);
      int l = tau_map(dir, sbase + s);
      atomicAdd(&ysum_f[((size_t)b * L_TOT + l) * 64 + d], y);   // non-returning
    }
  } else {
#pragma unroll 8
    for (int s = 0; s < CHUNK; ++s) {
      float u = __half2float(up[s * 64 + d]);
      float dt = __half2float(dtp[s * 64 + d]);
      float4 b0 = *(const float4*)(rp + s * 16);
      float4 b1 = *(const float4*)(rp + s * 16 + 4);
      float4 c0 = *(const float4*)(rp + s * 16 + 8);
      float4 c1 = *(const float4*)(rp + s * 16 + 12);
      float du = dt * u;
      float y = u * Dv;
      float bv[8] = {b0.x, b0.y, b0.z, b0.w, b1.x, b1.y, b1.z, b1.w};
      float cv[8] = {c0.x, c0.y, c0.z, c0.w, c1.x, c1.y, c1.z, c1.w};
#pragma unroll
      for (int n = 0; n < 8; ++n) {
        h[n] = fmaf(__expf(dt * a[n]), h[n], du * bv[n]);
        y = fmaf(cv[n], h[n], y);
      }
      int l = tau_map(dir, sbase + s);
      atomicAdd(&ysum_f[((size_t)b * L_TOT + l) * 64 + d], y);
    }
  }
}

// ---- F: /4 + LN + *silu(z) + out_proj + residual (reads pre-summed ysum) ----
__global__ void __launch_bounds__(256)
k_final(const float* __restrict__ ysum, const float* __restrict__ zbuf,
        const float* __restrict__ ong, const float* __restrict__ onb,
        const float* __restrict__ OW, const float* __restrict__ inp,
        float* __restrict__ out) {
  __shared__ float xt[64 * 65];
  __shared__ float tzw[64 * 65];
  __shared__ float st[640];
  const int t = threadIdx.x;
  const int lane = t & 63;
  const int w = t >> 6;
  const int b = blockIdx.x >> 8;
  const int l0 = (blockIdx.x & 255) << 6;
#pragma unroll 2
  for (int rep = 0; rep < 16; ++rep) {
    int r = rep * 4 + w;
    int l = l0 + r;
    xt[r * 65 + lane] = ysum[((size_t)b * L_TOT + l) * 64 + lane] * 0.25f;
    tzw[r * 65 + lane] = zbuf[((size_t)b * L_TOT + l) * 64 + lane];
  }
  __syncthreads();
  {
    float s1 = 0.f, s2 = 0.f;
    const int c0 = w * 16;
#pragma unroll
    for (int cc = 0; cc < 16; ++cc) {
      float v = xt[lane * 65 + c0 + cc];
      s1 += v; s2 = fmaf(v, v, s2);
    }
    st[w * 64 + lane] = s1;
    st[256 + w * 64 + lane] = s2;
  }
  __syncthreads();
  if (t < 64) {
    float s1 = st[t] + st[64 + t] + st[128 + t] + st[192 + t];
    float s2 = st[256 + t] + st[320 + t] + st[384 + t] + st[448 + t];
    float m = s1 * 0.015625f;
    float var = s2 * 0.015625f - m * m;
    st[512 + t] = m;
    st[576 + t] = rsqrtf(var + 1e-5f);
  }
  __syncthreads();
  {
    const float mv = st[512 + lane], rv = st[576 + lane];
#pragma unroll 4
    for (int k = 0; k < 16; ++k) {
      int c = w + 4 * k;
      float g = ong[c], bb = onb[c];
      float v = xt[lane * 65 + c];
      float zz = tzw[lane * 65 + c];
      xt[lane * 65 + c] = ((v - mv) * rv * g + bb) * silu_f(zz);
    }
  }
  __syncthreads();
#pragma unroll 4
  for (int rep = 0; rep < 16; ++rep) {
    int j = rep * 4 + w;
    tzw[j * 65 + lane] = OW[(size_t)j * 64 + lane];
  }
  __syncthreads();
  const int rg = lane & 15;
  const int jg = lane >> 4;
  const int j0 = w * 16 + jg * 4;
  const int r0 = rg * 4;
  float acc[4][4] = {};
#pragma unroll 2
  for (int c = 0; c < 64; ++c) {
    float xv[4], wv[4];
#pragma unroll
    for (int i = 0; i < 4; ++i) xv[i] = xt[(r0 + i) * 65 + c];
#pragma unroll
    for (int jj = 0; jj < 4; ++jj) wv[jj] = tzw[(j0 + jj) * 65 + c];
#pragma unroll
    for (int i = 0; i < 4; ++i)
#pragma unroll
      for (int jj = 0; jj < 4; ++jj) acc[i][jj] = fmaf(xv[i], wv[jj], acc[i][jj]);
  }
  __syncthreads();
#pragma unroll
  for (int i = 0; i < 4; ++i)
#pragma unroll
    for (int jj = 0; jj < 4; ++jj) xt[(j0 + jj) * 65 + r0 + i] = acc[i][jj];
  __syncthreads();
#pragma unroll 4
  for (int rep = 0; rep < 16; ++rep) {
    int j = rep * 4 + w;
    size_t o = ((size_t)b * 64 + j) * L_TOT + l0 + lane;
    out[o] = xt[j * 65 + lane] + inp[o];
  }
}

extern "C" void kernel_launch(void* const* d_in, const int* in_sizes, int n_in,
                              void* d_out, int out_size, void* d_ws, size_t ws_size,
                              hipStream_t stream) {
  const float* inp    = (const float*)d_in[0];
  const float* lng    = (const float*)d_in[1];
  const float* lnb    = (const float*)d_in[2];
  const float* ipw    = (const float*)d_in[3];
  const float* cw     = (const float*)d_in[4];
  const float* cb     = (const float*)d_in[5];
  const float* xpw    = (const float*)d_in[6];
  const float* dtw    = (const float*)d_in[7];
  const float* dtbias = (const float*)d_in[8];
  const float* alog   = (const float*)d_in[9];
  const float* dsk    = (const float*)d_in[10];
  const float* ong    = (const float*)d_in[11];
  const float* onb    = (const float*)d_in[12];
  const float* opw    = (const float*)d_in[13];
  float* out = (float*)d_out;
  float* ws = (float*)d_ws;

  // fp32: xbuf (reused as ysum), zbuf; fp16: 4x{xd, bc, dt, sdt, hc}.  ~59.2 MB.
  const size_t half_elems = 4 * (HSLOT_XD + HSLOT_BC + HSLOT_DT + SLOT_SDT + SLOT_HC);
  const size_t need_batched = 2 * SLOT_XD * sizeof(float) + half_elems * sizeof(__half);

  if (ws_size >= need_batched) {
    size_t off = 0;
    float* xbuf = ws + off; off += SLOT_XD;   // dead after convscan -> becomes ysum
    float* zbuf = ws + off; off += SLOT_XD;
    __half* hb = (__half*)(ws + off);
    size_t ho = 0;
    __half* xd  = hb + ho; ho += 4 * HSLOT_XD;
    __half* bc  = hb + ho; ho += 4 * HSLOT_BC;
    __half* dtb = hb + ho; ho += 4 * HSLOT_DT;
    __half* sdt = hb + ho; ho += 4 * SLOT_SDT;
    __half* hc  = hb + ho; ho += 4 * SLOT_HC;
    float* ysum = xbuf;

    k_ln_inproj<<<dim3(512), 256, 0, stream>>>(inp, lng, lnb, ipw, xbuf, zbuf);
    k_convscan<<<dim3(512, 4), 256, 0, stream>>>(xbuf, cw, cb, xpw, dtw, dtbias, alog,
                                                 xd, bc, dtb, hc, sdt, 0);
    hipMemsetAsync(ysum, 0, SLOT_XD * sizeof(float), stream);   // xbuf dead now
    k_scan2<<<dim3(512, 4, B_SZ), NCH, 0, stream>>>(hc, sdt, alog, 0);
    k_scan3<<<dim3(NCH / 4, 4, B_SZ), 256, 0, stream>>>(xd, bc, dtb, hc, alog, dsk,
                                                        ysum, 0);
    k_final<<<dim3(512), 256, 0, stream>>>(ysum, zbuf, ong, onb, opw, inp, out);
  } else {
    size_t off = 0;
    float* xbuf = ws + off; off += SLOT_XD;
    float* zbuf = ws + off; off += SLOT_XD;
    float* ysum = ws + off; off += SLOT_XD;
    __half* hb = (__half*)(ws + off);
    size_t ho = 0;
    __half* xd  = hb + ho; ho += HSLOT_XD;
    __half* bc  = hb + ho; ho += HSLOT_BC;
    __half* dtb = hb + ho; ho += HSLOT_DT;
    __half* sdt = hb + ho; ho += SLOT_SDT;
    __half* hc  = hb + ho; ho += SLOT_HC;

    hipMemsetAsync(ysum, 0, SLOT_XD * sizeof(float), stream);
    k_ln_inproj<<<dim3(512), 256, 0, stream>>>(inp, lng, lnb, ipw, xbuf, zbuf);
    for (int d2 = 0; d2 < 4; ++d2) {
      k_convscan<<<dim3(512, 1), 256, 0, stream>>>(xbuf, cw, cb, xpw, dtw, dtbias, alog,
                                                   xd, bc, dtb, hc, sdt, d2);
      k_scan2<<<dim3(512, 1, B_SZ), NCH, 0, stream>>>(hc, sdt, alog, d2);
      k_scan3<<<dim3(NCH / 4, 1, B_SZ), 256, 0, stream>>>(xd, bc, dtb, hc, alog, dsk,
                                                          ysum, d2);
    }
    k_final<<<dim3(512), 256, 0, stream>>>(ysum, zbuf, ong, onb, opw, inp, out);
  }
}

// Round 16
// 127.040 us; speedup vs baseline: 1.0645x; 1.0645x over previous
//
#include <hip/hip_runtime.h>
#include <hip/hip_bf16.h>
#include <hip/hip_fp16.h>
#include <cstdint>
#include <cstddef>

#define L_TOT 16384
#define B_SZ 2
#define NROW (B_SZ * L_TOT)
#define CHUNK 32
#define NCH (L_TOT / CHUNK)      // 512

static constexpr size_t SLOT_XD  = (size_t)NROW * 64;           // fp32 slots (xbuf/zbuf)
static constexpr size_t HSLOT_XD = (size_t)NROW * 64;           // xd (u), fp16, per dir
static constexpr size_t HSLOT_BC = (size_t)NROW * 16;           // B(8)+C(8), fp16, per dir
static constexpr size_t HSLOT_DT = (size_t)NROW * 64;           // dt (post-softplus), fp16
static constexpr size_t SLOT_SDT = (size_t)B_SZ * 64 * NCH;     // sum(dt), [b][d][ch], fp16
static constexpr size_t SLOT_HC  = (size_t)B_SZ * NCH * 64 * 8; // chunk h, [b][ch][d][n], fp16

union H8pack { float4 f4; __half2 h2[4]; };
union H4pack { float2 f2; __half2 h2[2]; };

typedef _Float16 h2v __attribute__((ext_vector_type(2)));
#if __has_builtin(__builtin_amdgcn_fdot2)
#define FDOT2(a, b, c) __builtin_amdgcn_fdot2((a), (b), (c), false)
#else
#define FDOT2(a, b, c) fmaf((float)(a)[0], (float)(b)[0], fmaf((float)(a)[1], (float)(b)[1], (c)))
#endif

// scan-position s -> original sequence index l (involution; verified rounds 1-2).
__device__ __forceinline__ int tau_map(int dir, int s) {
  int j = (dir & 1) ? (L_TOT - 1 - s) : s;
  if (dir >= 2) j = ((j & 127) << 7) | (j >> 7);   // transpose of 128x128
  return j;
}
__device__ __forceinline__ float silu_f(float x) { return x / (1.f + __expf(-x)); }
__device__ __forceinline__ float softplus_f(float x) {
  return fmaxf(x, 0.f) + __logf(1.f + __expf(-fabsf(x)));
}

// ---- A: LN + in_proj as LDS-tiled GEMM. 256 thr, 4x8 register sub-tile per thread. ----
__global__ void __launch_bounds__(256)
k_ln_inproj(const float* __restrict__ inp, const float* __restrict__ lng,
            const float* __restrict__ lnb, const float* __restrict__ W,
            float* __restrict__ xout, float* __restrict__ zout) {
  __shared__ float xt[64 * 65];        // input tile [l][c], pad 65 (conflict-free)
  __shared__ float wrk[8448];          // stats(640) -> W[128][65] -> so[64][132]
  const int t = threadIdx.x;
  const int lane = t & 63;
  const int w = t >> 6;
  const int b = blockIdx.x >> 8;
  const int l0 = (blockIdx.x & 255) << 6;
  const float* ip = inp + (size_t)b * 64 * L_TOT + l0 + lane;
#pragma unroll 4
  for (int cc = 0; cc < 16; ++cc) {
    int c = cc * 4 + w;
    xt[lane * 65 + c] = ip[(size_t)c * L_TOT];
  }
  __syncthreads();
  {
    float s1 = 0.f, s2 = 0.f;
    const int c0 = w * 16;
#pragma unroll
    for (int cc = 0; cc < 16; ++cc) {
      float v = xt[lane * 65 + c0 + cc];
      s1 += v; s2 = fmaf(v, v, s2);
    }
    wrk[w * 64 + lane] = s1;
    wrk[256 + w * 64 + lane] = s2;
  }
  __syncthreads();
  if (t < 64) {
    float s1 = wrk[t] + wrk[64 + t] + wrk[128 + t] + wrk[192 + t];
    float s2 = wrk[256 + t] + wrk[320 + t] + wrk[384 + t] + wrk[448 + t];
    float m = s1 * 0.015625f;
    float var = s2 * 0.015625f - m * m;
    wrk[512 + t] = m;
    wrk[576 + t] = rsqrtf(var + 1e-5f);
  }
  __syncthreads();
  {
    const float mv = wrk[512 + lane], rv = wrk[576 + lane];
#pragma unroll 4
    for (int k = 0; k < 16; ++k) {
      int c = w + 4 * k;
      float g = lng[c], bb = lnb[c];
      float v = xt[lane * 65 + c];
      xt[lane * 65 + c] = (v - mv) * rv * g + bb;
    }
  }
  __syncthreads();
#pragma unroll 4
  for (int rep = 0; rep < 32; ++rep) {
    int j = rep * 4 + w;
    wrk[j * 65 + lane] = W[(size_t)j * 64 + lane];
  }
  __syncthreads();
  const int rg = lane & 15;
  const int jg = lane >> 4;
  const int j0 = w * 32 + jg * 8;
  const int r0 = rg * 4;
  float acc[4][8] = {};
#pragma unroll 2
  for (int c = 0; c < 64; ++c) {
    float xv[4], wv[8];
#pragma unroll
    for (int i = 0; i < 4; ++i) xv[i] = xt[(r0 + i) * 65 + c];
#pragma unroll
    for (int jj = 0; jj < 8; ++jj) wv[jj] = wrk[(j0 + jj) * 65 + c];
#pragma unroll
    for (int i = 0; i < 4; ++i)
#pragma unroll
      for (int jj = 0; jj < 8; ++jj) acc[i][jj] = fmaf(xv[i], wv[jj], acc[i][jj]);
  }
  __syncthreads();
#pragma unroll
  for (int i = 0; i < 4; ++i)
#pragma unroll
    for (int jj = 0; jj < 8; ++jj) wrk[(r0 + i) * 132 + j0 + jj] = acc[i][jj];
  __syncthreads();
  float* xo = xout + ((size_t)b * L_TOT + l0) * 64;
  float* zo = zout + ((size_t)b * L_TOT + l0) * 64;
#pragma unroll 4
  for (int rep = 0; rep < 16; ++rep) {
    int r = rep * 4 + w;
    xo[(size_t)r * 64 + lane] = wrk[r * 132 + lane];
    zo[(size_t)r * 64 + lane] = wrk[r * 132 + 64 + lane];
  }
}

// ---- B: gather + conv(4) + SiLU + xproj(dot2) + dt precompute + fused scan1 ----
// (round-13 version: proven fastest; dt stored fp16 to global, reloaded by tail via L2)
__global__ void __launch_bounds__(256)
k_convscan(const float* __restrict__ xbuf, const float* __restrict__ cw,
           const float* __restrict__ cb, const float* __restrict__ xpw,
           const float* __restrict__ dtw, const float* __restrict__ dtbias,
           const float* __restrict__ alog,
           __half* __restrict__ xd_base, __half* __restrict__ bc_base,
           __half* __restrict__ dtb_base,
           __half* __restrict__ hcb, __half* __restrict__ sdtb, int dir_base) {
  __shared__ __align__(16) _Float16 xh[67 * 70];   // halo'd x tile -> u tile, fp16
  __shared__ __align__(16) _Float16 wt[20 * 70];   // xproj weights, fp16
  __shared__ __align__(16) float dbl[64 * 20];     // dtr+B+C rows, fp32
  const int t = threadIdx.x;
  const int lane = t & 63;
  const int w = t >> 6;
  const int slot = blockIdx.y;
  const int dir = dir_base + slot;
  const int blk = blockIdx.x;
  const int b = blk >> 8;
  const int s0 = (blk & 255) << 6;
  const float* xb = xbuf + (size_t)b * L_TOT * 64;
#pragma unroll 1
  for (int i = w; i < 67; i += 4) {
    int s = s0 - 3 + i;
    float v = 0.f;
    if (s >= 0) v = xb[(size_t)tau_map(dir, s) * 64 + lane];
    xh[i * 70 + lane] = (_Float16)v;
  }
#pragma unroll
  for (int jj = 0; jj < 5; ++jj) {
    int j = jj * 4 + w;
    wt[j * 70 + lane] = (_Float16)xpw[((size_t)dir * 20 + j) * 64 + lane];
  }
  __syncthreads();
  float wk[4];
#pragma unroll
  for (int k = 0; k < 4; ++k) wk[k] = cw[(dir * 64 + lane) * 4 + k];
  const float bconv = cb[dir * 64 + lane];
  float u[16];
  __half* xdp = xd_base + (size_t)slot * HSLOT_XD + ((size_t)b * L_TOT + s0) * 64;
#pragma unroll 4
  for (int rr = 0; rr < 16; ++rr) {
    const int r = rr * 4 + w;
    float acc = bconv;
#pragma unroll
    for (int k = 0; k < 4; ++k) acc = fmaf(wk[k], (float)xh[(r + k) * 70 + lane], acc);
    acc = silu_f(acc);
    u[rr] = acc;
    xdp[(size_t)r * 64 + lane] = __float2half(acc);
  }
  __syncthreads();   // conv reads of xh complete
#pragma unroll 4
  for (int rr = 0; rr < 16; ++rr) xh[(rr * 4 + w) * 70 + lane] = (_Float16)u[rr];
  __syncthreads();
  {  // xproj: wave w computes j = 5w..5w+4 for all 64 rows (row = lane), half2 dot2
    float acc5[5] = {0.f, 0.f, 0.f, 0.f, 0.f};
    const _Float16* xr = xh + lane * 70;
#pragma unroll 4
    for (int c2 = 0; c2 < 32; ++c2) {
      h2v xv = *(const h2v*)(xr + 2 * c2);
#pragma unroll
      for (int jj = 0; jj < 5; ++jj) {
        h2v wv = *(const h2v*)(wt + (w * 5 + jj) * 70 + 2 * c2);
        acc5[jj] = FDOT2(xv, wv, acc5[jj]);
      }
    }
#pragma unroll
    for (int jj = 0; jj < 5; ++jj) dbl[lane * 20 + w * 5 + jj] = acc5[jj];
  }
  __syncthreads();   // dbl complete (also fences xh u-tile)
  // bc store (B,C only, fp16)
  {
    __half* bcp = bc_base + (size_t)slot * HSLOT_BC + ((size_t)b * L_TOT + s0) * 16;
#pragma unroll
    for (int i = t; i < 1024; i += 256) {
      int r = i >> 4, j = i & 15;
      bcp[i] = __float2half(dbl[r * 20 + 4 + j]);
    }
  }
  // dt precompute: thread (lane=channel) does rows rr*4+w; fp16 to global
  __half* dtp = dtb_base + (size_t)slot * HSLOT_DT + ((size_t)b * L_TOT + s0) * 64;
  {
    float wdt[4];
#pragma unroll
    for (int r = 0; r < 4; ++r) wdt[r] = dtw[((size_t)dir * 64 + lane) * 4 + r];
    const float bia = dtbias[dir * 64 + lane];
#pragma unroll 4
    for (int rr = 0; rr < 16; ++rr) {
      const int r = rr * 4 + w;
      float dt = bia;
#pragma unroll
      for (int q = 0; q < 4; ++q) dt = fmaf(dbl[r * 20 + q], wdt[q], dt);
      dtp[(size_t)r * 64 + lane] = __float2half(softplus_f(dt));
    }
  }
  __syncthreads();   // dt writes drained -> L2-visible
  // ---- fused scan1: wave w scans chunk (w&1), states ng..ng+3; dt from global ----
  {
    const int w2 = w & 1;
    const int ng = (w >> 1) << 2;          // 0 or 4
    const int d = lane;
    const int ch = (s0 >> 5) + w2;
    const float* asrc = alog + ((size_t)dir * 64 + d) * 8;
    float a4[4];
#pragma unroll
    for (int k = 0; k < 4; ++k) a4[k] = -__expf(asrc[ng + k]);
    const float a0 = (ng == 0) ? a4[0] : -__expf(asrc[0]);
    bool pw = true;
#pragma unroll
    for (int k = 0; k < 4; ++k) {
      float tgt = (float)(ng + k + 1) * a0;
      pw = pw && (fabsf(a4[k] - tgt) <= 1e-3f * fabsf(tgt));
    }
    const _Float16* xs = xh + (w2 * 32) * 70;
    const float* ds = dbl + (w2 * 32) * 20;
    const __half* dts = dtp + (size_t)(w2 * 32) * 64;
    float h[4] = {0.f, 0.f, 0.f, 0.f};
    float sdt = 0.f;
    if (pw) {
#pragma unroll 8
      for (int s = 0; s < CHUNK; ++s) {
        float uu = (float)xs[s * 70 + d];
        float dt = __half2float(dts[s * 64 + d]);
        float4 bb = *(const float4*)(ds + s * 20 + 4 + ng);
        sdt += dt;
        float du = dt * uu;
        float p = __expf(dt * a0);
        float p2 = p * p, p4 = p2 * p2;
        float e0, e1, e2, e3;
        if (ng == 0) { e0 = p; e1 = p2; e2 = p2 * p; e3 = p4; }
        else { e0 = p4 * p; e1 = p4 * p2; e2 = e1 * p; e3 = p4 * p4; }
        h[0] = fmaf(e0, h[0], du * bb.x);
        h[1] = fmaf(e1, h[1], du * bb.y);
        h[2] = fmaf(e2, h[2], du * bb.z);
        h[3] = fmaf(e3, h[3], du * bb.w);
      }
    } else {
#pragma unroll 8
      for (int s = 0; s < CHUNK; ++s) {
        float uu = (float)xs[s * 70 + d];
        float dt = __half2float(dts[s * 64 + d]);
        float4 bb = *(const float4*)(ds + s * 20 + 4 + ng);
        sdt += dt;
        float du = dt * uu;
        h[0] = fmaf(__expf(dt * a4[0]), h[0], du * bb.x);
        h[1] = fmaf(__expf(dt * a4[1]), h[1], du * bb.y);
        h[2] = fmaf(__expf(dt * a4[2]), h[2], du * bb.z);
        h[3] = fmaf(__expf(dt * a4[3]), h[3], du * bb.w);
      }
    }
    if (ng == 0)
      sdtb[(size_t)slot * SLOT_SDT + ((size_t)b * 64 + d) * NCH + ch] = __float2half(sdt);
    H4pack pk;
    pk.h2[0] = __floats2half2_rn(h[0], h[1]);
    pk.h2[1] = __floats2half2_rn(h[2], h[3]);
    *(float2*)(hcb + (size_t)slot * SLOT_HC +
               (((size_t)b * NCH + ch) * 64 + d) * 8 + ng) = pk.f2;
  }
}

// ---- S2: parallel chunk stitch (Hillis-Steele over 512 chunks), exclusive in-place ----
__global__ void __launch_bounds__(512)
k_scan2(__half* __restrict__ hcb, const __half* __restrict__ sdtb,
        const float* __restrict__ alog, int dir_base) {
  const int t = threadIdx.x;           // 512 = chunk index
  const int d = blockIdx.x >> 3;
  const int n = blockIdx.x & 7;
  const int slot = blockIdx.y;
  const int dir = dir_base + slot;
  const int b = blockIdx.z;
  const float a = -__expf(alog[((size_t)dir * 64 + d) * 8 + n]);
  __half* hcp = hcb + (size_t)slot * SLOT_HC + (size_t)b * NCH * 512;
  const __half* sdp = sdtb + (size_t)slot * SLOT_SDT + ((size_t)b * 64 + d) * NCH;
  float e = __expf(a * __half2float(sdp[t]));         // coalesced
  float v = __half2float(hcp[((size_t)t * 64 + d) * 8 + n]);
  __shared__ float sE[NCH], sV[NCH];
  sE[t] = e; sV[t] = v;
  __syncthreads();
#pragma unroll
  for (int off = 1; off < NCH; off <<= 1) {
    float pe = 1.f, pv = 0.f;
    if (t >= off) { pe = sE[t - off]; pv = sV[t - off]; }
    __syncthreads();
    v = fmaf(e, pv, v);     // compose: prev then self
    e = e * pe;
    sE[t] = e; sV[t] = v;
    __syncthreads();
  }
  const float hs = (t == 0) ? 0.f : sV[t - 1];   // exclusive = h_start for chunk t
  hcp[((size_t)t * 64 + d) * 8 + n] = __float2half(hs);
}

// ---- S3: final scan; y written fp16 at tau-mapped row per-dir (fire-and-forget
// scattered STORES instead of k_final's blocking scattered READS). ----
__global__ void __launch_bounds__(256, 4)
k_scan3(const __half* __restrict__ xd_in, const __half* __restrict__ bc_base,
        const __half* __restrict__ dtb_base, const __half* __restrict__ hcb,
        const float* __restrict__ alog, const float* __restrict__ dsk,
        float* __restrict__ ysum_f, __half* __restrict__ y_h,
        int dir_base, int scatter) {
  __shared__ __align__(16) float rpl[4 * CHUNK * 16];   // 8 KB (B,C)
  const int t = threadIdx.x;
  const int w = t >> 6;
  const int d = t & 63;
  const int ch = blockIdx.x * 4 + w;
  const int slot = blockIdx.y;
  const int dir = dir_base + slot;
  const int b = blockIdx.z;
  const __half* bcblk = bc_base + (size_t)slot * HSLOT_BC +
                        ((size_t)b * L_TOT + (size_t)blockIdx.x * 4 * CHUNK) * 16;
#pragma unroll
  for (int i = t; i < 4 * CHUNK * 16; i += 256) rpl[i] = __half2float(bcblk[i]);
  __syncthreads();
  const float* rp = rpl + w * CHUNK * 16;
  float a[8];
#pragma unroll
  for (int n = 0; n < 8; ++n) a[n] = -__expf(alog[((size_t)dir * 64 + d) * 8 + n]);
  const float a0 = a[0];
  bool pw = true;
#pragma unroll
  for (int n = 0; n < 8; ++n) {
    float tgt = (float)(n + 1) * a0;
    pw = pw && (fabsf(a[n] - tgt) <= 1e-3f * fabsf(tgt));
  }
  const float Dv = dsk[dir * 64 + d];
  const __half* up  = xd_in + (size_t)slot * HSLOT_XD + ((size_t)b * L_TOT + ch * CHUNK) * 64;
  const __half* dtp = dtb_base + (size_t)slot * HSLOT_DT + ((size_t)b * L_TOT + ch * CHUNK) * 64;
  float h[8];
  {
    H8pack pk;
    pk.f4 = *(const float4*)(hcb + (size_t)slot * SLOT_HC +
                             (((size_t)b * NCH + ch) * 64 + d) * 8);
#pragma unroll
    for (int k = 0; k < 4; ++k) {
      h[2 * k] = __low2float(pk.h2[k]);
      h[2 * k + 1] = __high2float(pk.h2[k]);
    }
  }
  const int sbase = ch * CHUNK;
  if (pw) {
#pragma unroll 8
    for (int s = 0; s < CHUNK; ++s) {
      float u = __half2float(up[s * 64 + d]);
      float dt = __half2float(dtp[s * 64 + d]);
      float4 b0 = *(const float4*)(rp + s * 16);
      float4 b1 = *(const float4*)(rp + s * 16 + 4);
      float4 c0 = *(const float4*)(rp + s * 16 + 8);
      float4 c1 = *(const float4*)(rp + s * 16 + 12);
      float du = dt * u;
      float p = __expf(dt * a0);
      float p2 = p * p, p3 = p2 * p, p4 = p2 * p2;
      float p5 = p4 * p, p6 = p4 * p2, p7 = p4 * p3, p8 = p4 * p4;
      h[0] = fmaf(p,  h[0], du * b0.x);
      h[1] = fmaf(p2, h[1], du * b0.y);
      h[2] = fmaf(p3, h[2], du * b0.z);
      h[3] = fmaf(p4, h[3], du * b0.w);
      h[4] = fmaf(p5, h[4], du * b1.x);
      h[5] = fmaf(p6, h[5], du * b1.y);
      h[6] = fmaf(p7, h[6], du * b1.z);
      h[7] = fmaf(p8, h[7], du * b1.w);
      float y = u * Dv;
      y = fmaf(c0.x, h[0], y); y = fmaf(c0.y, h[1], y);
      y = fmaf(c0.z, h[2], y); y = fmaf(c0.w, h[3], y);
      y = fmaf(c1.x, h[4], y); y = fmaf(c1.y, h[5], y);
      y = fmaf(c1.z, h[6], y); y = fmaf(c1.w, h[7], y);
      int l = tau_map(dir, sbase + s);
      if (scatter) {
        ysum_f[((size_t)b * L_TOT + l) * 64 + d] += y;   // fallback: dirs serialized
      } else {
        y_h[(size_t)slot * HSLOT_XD + ((size_t)b * L_TOT + l) * 64 + d] = __float2half(y);
      }
    }
  } else {
#pragma unroll 8
    for (int s = 0; s < CHUNK; ++s) {
      float u = __half2float(up[s * 64 + d]);
      float dt = __half2float(dtp[s * 64 + d]);
      float4 b0 = *(const float4*)(rp + s * 16);
      float4 b1 = *(const float4*)(rp + s * 16 + 4);
      float4 c0 = *(const float4*)(rp + s * 16 + 8);
      float4 c1 = *(const float4*)(rp + s * 16 + 12);
      float du = dt * u;
      float y = u * Dv;
      float bv[8] = {b0.x, b0.y, b0.z, b0.w, b1.x, b1.y, b1.z, b1.w};
      float cv[8] = {c0.x, c0.y, c0.z, c0.w, c1.x, c1.y, c1.z, c1.w};
#pragma unroll
      for (int n = 0; n < 8; ++n) {
        h[n] = fmaf(__expf(dt * a[n]), h[n], du * bv[n]);
        y = fmaf(cv[n], h[n], y);
      }
      int l = tau_map(dir, sbase + s);
      if (scatter) {
        ysum_f[((size_t)b * L_TOT + l) * 64 + d] += y;
      } else {
        y_h[(size_t)slot * HSLOT_XD + ((size_t)b * L_TOT + l) * 64 + d] = __float2half(y);
      }
    }
  }
}

// ---- F: sum 4 coalesced per-dir y slots + /4 + LN + *silu(z) + out_proj + residual ----
__global__ void __launch_bounds__(256)
k_final(const __half* __restrict__ yh, const float* __restrict__ ysum,
        const float* __restrict__ zbuf,
        const float* __restrict__ ong, const float* __restrict__ onb,
        const float* __restrict__ OW, const float* __restrict__ inp,
        float* __restrict__ out, int gather) {
  __shared__ float xt[64 * 65];
  __shared__ float tzw[64 * 65];
  __shared__ float st[640];
  const int t = threadIdx.x;
  const int lane = t & 63;
  const int w = t >> 6;
  const int b = blockIdx.x >> 8;
  const int l0 = (blockIdx.x & 255) << 6;
#pragma unroll 2
  for (int rep = 0; rep < 16; ++rep) {
    int r = rep * 4 + w;
    int l = l0 + r;
    float acc;
    if (gather) {
      acc = 0.f;
#pragma unroll
      for (int dir = 0; dir < 4; ++dir)   // 4 coalesced same-row reads (no tau)
        acc += __half2float(yh[(size_t)dir * HSLOT_XD + ((size_t)b * L_TOT + l) * 64 + lane]);
    } else {
      acc = ysum[((size_t)b * L_TOT + l) * 64 + lane];
    }
    xt[r * 65 + lane] = acc * 0.25f;
    tzw[r * 65 + lane] = zbuf[((size_t)b * L_TOT + l) * 64 + lane];
  }
  __syncthreads();
  {
    float s1 = 0.f, s2 = 0.f;
    const int c0 = w * 16;
#pragma unroll
    for (int cc = 0; cc < 16; ++cc) {
      float v = xt[lane * 65 + c0 + cc];
      s1 += v; s2 = fmaf(v, v, s2);
    }
    st[w * 64 + lane] = s1;
    st[256 + w * 64 + lane] = s2;
  }
  __syncthreads();
  if (t < 64) {
    float s1 = st[t] + st[64 + t] + st[128 + t] + st[192 + t];
    float s2 = st[256 + t] + st[320 + t] + st[384 + t] + st[448 + t];
    float m = s1 * 0.015625f;
    float var = s2 * 0.015625f - m * m;
    st[512 + t] = m;
    st[576 + t] = rsqrtf(var + 1e-5f);
  }
  __syncthreads();
  {
    const float mv = st[512 + lane], rv = st[576 + lane];
#pragma unroll 4
    for (int k = 0; k < 16; ++k) {
      int c = w + 4 * k;
      float g = ong[c], bb = onb[c];
      float v = xt[lane * 65 + c];
      float zz = tzw[lane * 65 + c];
      xt[lane * 65 + c] = ((v - mv) * rv * g + bb) * silu_f(zz);
    }
  }
  __syncthreads();
#pragma unroll 4
  for (int rep = 0; rep < 16; ++rep) {
    int j = rep * 4 + w;
    tzw[j * 65 + lane] = OW[(size_t)j * 64 + lane];
  }
  __syncthreads();
  const int rg = lane & 15;
  const int jg = lane >> 4;
  const int j0 = w * 16 + jg * 4;
  const int r0 = rg * 4;
  float acc[4][4] = {};
#pragma unroll 2
  for (int c = 0; c < 64; ++c) {
    float xv[4], wv[4];
#pragma unroll
    for (int i = 0; i < 4; ++i) xv[i] = xt[(r0 + i) * 65 + c];
#pragma unroll
    for (int jj = 0; jj < 4; ++jj) wv[jj] = tzw[(j0 + jj) * 65 + c];
#pragma unroll
    for (int i = 0; i < 4; ++i)
#pragma unroll
      for (int jj = 0; jj < 4; ++jj) acc[i][jj] = fmaf(xv[i], wv[jj], acc[i][jj]);
  }
  __syncthreads();
#pragma unroll
  for (int i = 0; i < 4; ++i)
#pragma unroll
    for (int jj = 0; jj < 4; ++jj) xt[(j0 + jj) * 65 + r0 + i] = acc[i][jj];
  __syncthreads();
#pragma unroll 4
  for (int rep = 0; rep < 16; ++rep) {
    int j = rep * 4 + w;
    size_t o = ((size_t)b * 64 + j) * L_TOT + l0 + lane;
    out[o] = xt[j * 65 + lane] + inp[o];
  }
}

extern "C" void kernel_launch(void* const* d_in, const int* in_sizes, int n_in,
                              void* d_out, int out_size, void* d_ws, size_t ws_size,
                              hipStream_t stream) {
  const float* inp    = (const float*)d_in[0];
  const float* lng    = (const float*)d_in[1];
  const float* lnb    = (const float*)d_in[2];
  const float* ipw    = (const float*)d_in[3];
  const float* cw     = (const float*)d_in[4];
  const float* cb     = (const float*)d_in[5];
  const float* xpw    = (const float*)d_in[6];
  const float* dtw    = (const float*)d_in[7];
  const float* dtbias = (const float*)d_in[8];
  const float* alog   = (const float*)d_in[9];
  const float* dsk    = (const float*)d_in[10];
  const float* ong    = (const float*)d_in[11];
  const float* onb    = (const float*)d_in[12];
  const float* opw    = (const float*)d_in[13];
  float* out = (float*)d_out;
  float* ws = (float*)d_ws;

  // fp32: xbuf (reused as fp16 y_h after convscan), zbuf; fp16: 4x{xd,bc,dt,sdt,hc}.
  const size_t half_elems = 4 * (HSLOT_XD + HSLOT_BC + HSLOT_DT + SLOT_SDT + SLOT_HC);
  const size_t need_batched = 2 * SLOT_XD * sizeof(float) + half_elems * sizeof(__half);

  if (ws_size >= need_batched) {
    size_t off = 0;
    float* xbuf = ws + off; off += SLOT_XD;   // dead after convscan -> y_h (4 fp16 slots)
    float* zbuf = ws + off; off += SLOT_XD;
    __half* hb = (__half*)(ws + off);
    size_t ho = 0;
    __half* xd  = hb + ho; ho += 4 * HSLOT_XD;
    __half* bc  = hb + ho; ho += 4 * HSLOT_BC;
    __half* dtb = hb + ho; ho += 4 * HSLOT_DT;
    __half* sdt = hb + ho; ho += 4 * SLOT_SDT;
    __half* hc  = hb + ho; ho += 4 * SLOT_HC;
    __half* y_h = (__half*)xbuf;              // 4 * HSLOT_XD halves == SLOT_XD floats

    k_ln_inproj<<<dim3(512), 256, 0, stream>>>(inp, lng, lnb, ipw, xbuf, zbuf);
    k_convscan<<<dim3(512, 4), 256, 0, stream>>>(xbuf, cw, cb, xpw, dtw, dtbias, alog,
                                                 xd, bc, dtb, hc, sdt, 0);
    k_scan2<<<dim3(512, 4, B_SZ), NCH, 0, stream>>>(hc, sdt, alog, 0);
    k_scan3<<<dim3(NCH / 4, 4, B_SZ), 256, 0, stream>>>(xd, bc, dtb, hc, alog, dsk,
                                                        nullptr, y_h, 0, 0);
    k_final<<<dim3(512), 256, 0, stream>>>(y_h, nullptr, zbuf, ong, onb, opw, inp, out, 1);
  } else {
    size_t off = 0;
    float* xbuf = ws + off; off += SLOT_XD;
    float* zbuf = ws + off; off += SLOT_XD;
    float* ysum = ws + off; off += SLOT_XD;
    __half* hb = (__half*)(ws + off);
    size_t ho = 0;
    __half* xd  = hb + ho; ho += HSLOT_XD;
    __half* bc  = hb + ho; ho += HSLOT_BC;
    __half* dtb = hb + ho; ho += HSLOT_DT;
    __half* sdt = hb + ho; ho += SLOT_SDT;
    __half* hc  = hb + ho; ho += SLOT_HC;

    hipMemsetAsync(ysum, 0, SLOT_XD * sizeof(float), stream);
    k_ln_inproj<<<dim3(512), 256, 0, stream>>>(inp, lng, lnb, ipw, xbuf, zbuf);
    for (int d2 = 0; d2 < 4; ++d2) {
      k_convscan<<<dim3(512, 1), 256, 0, stream>>>(xbuf, cw, cb, xpw, dtw, dtbias, alog,
                                                   xd, bc, dtb, hc, sdt, d2);
      k_scan2<<<dim3(512, 1, B_SZ), NCH, 0, stream>>>(hc, sdt, alog, d2);
      k_scan3<<<dim3(NCH / 4, 1, B_SZ), 256, 0, stream>>>(xd, bc, dtb, hc, alog, dsk,
                                                          ysum, nullptr, d2, 1);
    }
    k_final<<<dim3(512), 256, 0, stream>>>(nullptr, ysum, zbuf, ong, onb, opw, inp, out, 0);
  }
}

// Round 17
// 124.788 us; speedup vs baseline: 1.0837x; 1.0180x over previous
//
#include <hip/hip_runtime.h>
#include <hip/hip_bf16.h>
#include <hip/hip_fp16.h>
#include <cstdint>
#include <cstddef>

#define L_TOT 16384
#define B_SZ 2
#define NROW (B_SZ * L_TOT)
#define CHUNK 32
#define NCH (L_TOT / CHUNK)      // 512

static constexpr size_t SLOT_XD  = (size_t)NROW * 64;           // fp32 slots (xbuf/zbuf)
static constexpr size_t HSLOT_XD = (size_t)NROW * 64;           // xd (u) -> y, fp16, per dir
static constexpr size_t HSLOT_BC = (size_t)NROW * 16;           // B(8)+C(8), fp16, per dir
static constexpr size_t HSLOT_DT = (size_t)NROW * 64;           // dt (post-softplus), fp16
static constexpr size_t SLOT_SDT = (size_t)B_SZ * 64 * NCH;     // sum(dt), [b][d][ch], fp16
static constexpr size_t SLOT_HC  = (size_t)B_SZ * NCH * 64 * 8; // chunk h, [b][ch][d][n], fp16

union H8pack { float4 f4; __half2 h2[4]; };
union H4pack { float2 f2; __half2 h2[2]; };

typedef _Float16 h2v __attribute__((ext_vector_type(2)));
#if __has_builtin(__builtin_amdgcn_fdot2)
#define FDOT2(a, b, c) __builtin_amdgcn_fdot2((a), (b), (c), false)
#else
#define FDOT2(a, b, c) fmaf((float)(a)[0], (float)(b)[0], fmaf((float)(a)[1], (float)(b)[1], (c)))
#endif

// scan-position s -> original sequence index l (involution; verified rounds 1-2).
__device__ __forceinline__ int tau_map(int dir, int s) {
  int j = (dir & 1) ? (L_TOT - 1 - s) : s;
  if (dir >= 2) j = ((j & 127) << 7) | (j >> 7);   // transpose of 128x128
  return j;
}
__device__ __forceinline__ float silu_f(float x) { return x / (1.f + __expf(-x)); }
__device__ __forceinline__ float softplus_f(float x) {
  return fmaxf(x, 0.f) + __logf(1.f + __expf(-fabsf(x)));
}

// ---- A: LN + in_proj as LDS-tiled GEMM. 256 thr, 4x8 register sub-tile per thread. ----
__global__ void __launch_bounds__(256)
k_ln_inproj(const float* __restrict__ inp, const float* __restrict__ lng,
            const float* __restrict__ lnb, const float* __restrict__ W,
            float* __restrict__ xout, float* __restrict__ zout) {
  __shared__ float xt[64 * 65];        // input tile [l][c], pad 65 (conflict-free)
  __shared__ float wrk[8448];          // stats(640) -> W[128][65] -> so[64][132]
  const int t = threadIdx.x;
  const int lane = t & 63;
  const int w = t >> 6;
  const int b = blockIdx.x >> 8;
  const int l0 = (blockIdx.x & 255) << 6;
  const float* ip = inp + (size_t)b * 64 * L_TOT + l0 + lane;
#pragma unroll 4
  for (int cc = 0; cc < 16; ++cc) {
    int c = cc * 4 + w;
    xt[lane * 65 + c] = ip[(size_t)c * L_TOT];
  }
  __syncthreads();
  {
    float s1 = 0.f, s2 = 0.f;
    const int c0 = w * 16;
#pragma unroll
    for (int cc = 0; cc < 16; ++cc) {
      float v = xt[lane * 65 + c0 + cc];
      s1 += v; s2 = fmaf(v, v, s2);
    }
    wrk[w * 64 + lane] = s1;
    wrk[256 + w * 64 + lane] = s2;
  }
  __syncthreads();
  if (t < 64) {
    float s1 = wrk[t] + wrk[64 + t] + wrk[128 + t] + wrk[192 + t];
    float s2 = wrk[256 + t] + wrk[320 + t] + wrk[384 + t] + wrk[448 + t];
    float m = s1 * 0.015625f;
    float var = s2 * 0.015625f - m * m;
    wrk[512 + t] = m;
    wrk[576 + t] = rsqrtf(var + 1e-5f);
  }
  __syncthreads();
  {
    const float mv = wrk[512 + lane], rv = wrk[576 + lane];
#pragma unroll 4
    for (int k = 0; k < 16; ++k) {
      int c = w + 4 * k;
      float g = lng[c], bb = lnb[c];
      float v = xt[lane * 65 + c];
      xt[lane * 65 + c] = (v - mv) * rv * g + bb;
    }
  }
  __syncthreads();
#pragma unroll 4
  for (int rep = 0; rep < 32; ++rep) {
    int j = rep * 4 + w;
    wrk[j * 65 + lane] = W[(size_t)j * 64 + lane];
  }
  __syncthreads();
  const int rg = lane & 15;
  const int jg = lane >> 4;
  const int j0 = w * 32 + jg * 8;
  const int r0 = rg * 4;
  float acc[4][8] = {};
#pragma unroll 2
  for (int c = 0; c < 64; ++c) {
    float xv[4], wv[8];
#pragma unroll
    for (int i = 0; i < 4; ++i) xv[i] = xt[(r0 + i) * 65 + c];
#pragma unroll
    for (int jj = 0; jj < 8; ++jj) wv[jj] = wrk[(j0 + jj) * 65 + c];
#pragma unroll
    for (int i = 0; i < 4; ++i)
#pragma unroll
      for (int jj = 0; jj < 8; ++jj) acc[i][jj] = fmaf(xv[i], wv[jj], acc[i][jj]);
  }
  __syncthreads();
#pragma unroll
  for (int i = 0; i < 4; ++i)
#pragma unroll
    for (int jj = 0; jj < 8; ++jj) wrk[(r0 + i) * 132 + j0 + jj] = acc[i][jj];
  __syncthreads();
  float* xo = xout + ((size_t)b * L_TOT + l0) * 64;
  float* zo = zout + ((size_t)b * L_TOT + l0) * 64;
#pragma unroll 4
  for (int rep = 0; rep < 16; ++rep) {
    int r = rep * 4 + w;
    xo[(size_t)r * 64 + lane] = wrk[r * 132 + lane];
    zo[(size_t)r * 64 + lane] = wrk[r * 132 + 64 + lane];
  }
}

// ---- B: gather + conv(4) + SiLU + xproj(dot2) + dt precompute + fused scan1 ----
// dt computed ONCE (fp16, stored to global) and consumed by both the fused tail
// (via L2-hot reload) and scan3 -- removes per-step softplus everywhere downstream.
__global__ void __launch_bounds__(256)
k_convscan(const float* __restrict__ xbuf, const float* __restrict__ cw,
           const float* __restrict__ cb, const float* __restrict__ xpw,
           const float* __restrict__ dtw, const float* __restrict__ dtbias,
           const float* __restrict__ alog,
           __half* __restrict__ xd_base, __half* __restrict__ bc_base,
           __half* __restrict__ dtb_base,
           __half* __restrict__ hcb, __half* __restrict__ sdtb, int dir_base) {
  __shared__ __align__(16) _Float16 xh[67 * 70];   // halo'd x tile -> u tile, fp16
  __shared__ __align__(16) _Float16 wt[20 * 70];   // xproj weights, fp16
  __shared__ __align__(16) float dbl[64 * 20];     // dtr+B+C rows, fp32
  const int t = threadIdx.x;
  const int lane = t & 63;
  const int w = t >> 6;
  const int slot = blockIdx.y;
  const int dir = dir_base + slot;
  const int blk = blockIdx.x;
  const int b = blk >> 8;
  const int s0 = (blk & 255) << 6;
  const float* xb = xbuf + (size_t)b * L_TOT * 64;
#pragma unroll 1
  for (int i = w; i < 67; i += 4) {
    int s = s0 - 3 + i;
    float v = 0.f;
    if (s >= 0) v = xb[(size_t)tau_map(dir, s) * 64 + lane];
    xh[i * 70 + lane] = (_Float16)v;
  }
#pragma unroll
  for (int jj = 0; jj < 5; ++jj) {
    int j = jj * 4 + w;
    wt[j * 70 + lane] = (_Float16)xpw[((size_t)dir * 20 + j) * 64 + lane];
  }
  __syncthreads();
  float wk[4];
#pragma unroll
  for (int k = 0; k < 4; ++k) wk[k] = cw[(dir * 64 + lane) * 4 + k];
  const float bconv = cb[dir * 64 + lane];
  float u[16];
  __half* xdp = xd_base + (size_t)slot * HSLOT_XD + ((size_t)b * L_TOT + s0) * 64;
#pragma unroll 4
  for (int rr = 0; rr < 16; ++rr) {
    const int r = rr * 4 + w;
    float acc = bconv;
#pragma unroll
    for (int k = 0; k < 4; ++k) acc = fmaf(wk[k], (float)xh[(r + k) * 70 + lane], acc);
    acc = silu_f(acc);
    u[rr] = acc;
    xdp[(size_t)r * 64 + lane] = __float2half(acc);
  }
  __syncthreads();   // conv reads of xh complete
#pragma unroll 4
  for (int rr = 0; rr < 16; ++rr) xh[(rr * 4 + w) * 70 + lane] = (_Float16)u[rr];
  __syncthreads();
  {  // xproj: wave w computes j = 5w..5w+4 for all 64 rows (row = lane), half2 dot2
    float acc5[5] = {0.f, 0.f, 0.f, 0.f, 0.f};
    const _Float16* xr = xh + lane * 70;
#pragma unroll 4
    for (int c2 = 0; c2 < 32; ++c2) {
      h2v xv = *(const h2v*)(xr + 2 * c2);
#pragma unroll
      for (int jj = 0; jj < 5; ++jj) {
        h2v wv = *(const h2v*)(wt + (w * 5 + jj) * 70 + 2 * c2);
        acc5[jj] = FDOT2(xv, wv, acc5[jj]);
      }
    }
#pragma unroll
    for (int jj = 0; jj < 5; ++jj) dbl[lane * 20 + w * 5 + jj] = acc5[jj];
  }
  __syncthreads();   // dbl complete (also fences xh u-tile)
  // bc store (B,C only, fp16)
  {
    __half* bcp = bc_base + (size_t)slot * HSLOT_BC + ((size_t)b * L_TOT + s0) * 16;
#pragma unroll
    for (int i = t; i < 1024; i += 256) {
      int r = i >> 4, j = i & 15;
      bcp[i] = __float2half(dbl[r * 20 + 4 + j]);
    }
  }
  // dt precompute: thread (lane=channel) does rows rr*4+w; fp16 to global
  __half* dtp = dtb_base + (size_t)slot * HSLOT_DT + ((size_t)b * L_TOT + s0) * 64;
  {
    float wdt[4];
#pragma unroll
    for (int r = 0; r < 4; ++r) wdt[r] = dtw[((size_t)dir * 64 + lane) * 4 + r];
    const float bia = dtbias[dir * 64 + lane];
#pragma unroll 4
    for (int rr = 0; rr < 16; ++rr) {
      const int r = rr * 4 + w;
      float dt = bia;
#pragma unroll
      for (int q = 0; q < 4; ++q) dt = fmaf(dbl[r * 20 + q], wdt[q], dt);
      dtp[(size_t)r * 64 + lane] = __float2half(softplus_f(dt));
    }
  }
  __syncthreads();   // dt writes drained -> L2-visible
  // ---- fused scan1: wave w scans chunk (w&1), states ng..ng+3; dt from global ----
  {
    const int w2 = w & 1;
    const int ng = (w >> 1) << 2;          // 0 or 4
    const int d = lane;
    const int ch = (s0 >> 5) + w2;
    const float* asrc = alog + ((size_t)dir * 64 + d) * 8;
    float a4[4];
#pragma unroll
    for (int k = 0; k < 4; ++k) a4[k] = -__expf(asrc[ng + k]);
    const float a0 = (ng == 0) ? a4[0] : -__expf(asrc[0]);
    bool pw = true;
#pragma unroll
    for (int k = 0; k < 4; ++k) {
      float tgt = (float)(ng + k + 1) * a0;
      pw = pw && (fabsf(a4[k] - tgt) <= 1e-3f * fabsf(tgt));
    }
    const _Float16* xs = xh + (w2 * 32) * 70;
    const float* ds = dbl + (w2 * 32) * 20;
    const __half* dts = dtp + (size_t)(w2 * 32) * 64;
    float h[4] = {0.f, 0.f, 0.f, 0.f};
    float sdt = 0.f;
    if (pw) {
#pragma unroll 8
      for (int s = 0; s < CHUNK; ++s) {
        float uu = (float)xs[s * 70 + d];
        float dt = __half2float(dts[s * 64 + d]);
        float4 bb = *(const float4*)(ds + s * 20 + 4 + ng);
        sdt += dt;
        float du = dt * uu;
        float p = __expf(dt * a0);
        float p2 = p * p, p4 = p2 * p2;
        float e0, e1, e2, e3;
        if (ng == 0) { e0 = p; e1 = p2; e2 = p2 * p; e3 = p4; }
        else { e0 = p4 * p; e1 = p4 * p2; e2 = e1 * p; e3 = p4 * p4; }
        h[0] = fmaf(e0, h[0], du * bb.x);
        h[1] = fmaf(e1, h[1], du * bb.y);
        h[2] = fmaf(e2, h[2], du * bb.z);
        h[3] = fmaf(e3, h[3], du * bb.w);
      }
    } else {
#pragma unroll 8
      for (int s = 0; s < CHUNK; ++s) {
        float uu = (float)xs[s * 70 + d];
        float dt = __half2float(dts[s * 64 + d]);
        float4 bb = *(const float4*)(ds + s * 20 + 4 + ng);
        sdt += dt;
        float du = dt * uu;
        h[0] = fmaf(__expf(dt * a4[0]), h[0], du * bb.x);
        h[1] = fmaf(__expf(dt * a4[1]), h[1], du * bb.y);
        h[2] = fmaf(__expf(dt * a4[2]), h[2], du * bb.z);
        h[3] = fmaf(__expf(dt * a4[3]), h[3], du * bb.w);
      }
    }
    if (ng == 0)
      sdtb[(size_t)slot * SLOT_SDT + ((size_t)b * 64 + d) * NCH + ch] = __float2half(sdt);
    H4pack pk;
    pk.h2[0] = __floats2half2_rn(h[0], h[1]);
    pk.h2[1] = __floats2half2_rn(h[2], h[3]);
    *(float2*)(hcb + (size_t)slot * SLOT_HC +
               (((size_t)b * NCH + ch) * 64 + d) * 8 + ng) = pk.f2;
  }
}

// ---- S2: parallel chunk stitch (Hillis-Steele over 512 chunks), exclusive in-place ----
__global__ void __launch_bounds__(512)
k_scan2(__half* __restrict__ hcb, const __half* __restrict__ sdtb,
        const float* __restrict__ alog, int dir_base) {
  const int t = threadIdx.x;           // 512 = chunk index
  const int d = blockIdx.x >> 3;
  const int n = blockIdx.x & 7;
  const int slot = blockIdx.y;
  const int dir = dir_base + slot;
  const int b = blockIdx.z;
  const float a = -__expf(alog[((size_t)dir * 64 + d) * 8 + n]);
  __half* hcp = hcb + (size_t)slot * SLOT_HC + (size_t)b * NCH * 512;
  const __half* sdp = sdtb + (size_t)slot * SLOT_SDT + ((size_t)b * 64 + d) * NCH;
  float e = __expf(a * __half2float(sdp[t]));         // coalesced
  float v = __half2float(hcp[((size_t)t * 64 + d) * 8 + n]);
  __shared__ float sE[NCH], sV[NCH];
  sE[t] = e; sV[t] = v;
  __syncthreads();
#pragma unroll
  for (int off = 1; off < NCH; off <<= 1) {
    float pe = 1.f, pv = 0.f;
    if (t >= off) { pe = sE[t - off]; pv = sV[t - off]; }
    __syncthreads();
    v = fmaf(e, pv, v);     // compose: prev then self
    e = e * pe;
    sE[t] = e; sV[t] = v;
    __syncthreads();
  }
  const float hs = (t == 0) ? 0.f : sV[t - 1];   // exclusive = h_start for chunk t
  hcp[((size_t)t * 64 + d) * 8 + n] = __float2half(hs);
}

// ---- S3: final scan; u/dt from fp16 globals, B/C staged in LDS; y fp16 (or scatter) ----
__global__ void __launch_bounds__(256, 4)
k_scan3(const __half* __restrict__ xd_in, const __half* __restrict__ bc_base,
        const __half* __restrict__ dtb_base, const __half* __restrict__ hcb,
        const float* __restrict__ alog, const float* __restrict__ dsk,
        float* __restrict__ ysum_f, __half* __restrict__ y_h,
        int dir_base, int scatter) {
  __shared__ __align__(16) float rpl[4 * CHUNK * 16];   // 8 KB (B,C)
  const int t = threadIdx.x;
  const int w = t >> 6;
  const int d = t & 63;
  const int ch = blockIdx.x * 4 + w;
  const int slot = blockIdx.y;
  const int dir = dir_base + slot;
  const int b = blockIdx.z;
  const __half* bcblk = bc_base + (size_t)slot * HSLOT_BC +
                        ((size_t)b * L_TOT + (size_t)blockIdx.x * 4 * CHUNK) * 16;
#pragma unroll
  for (int i = t; i < 4 * CHUNK * 16; i += 256) rpl[i] = __half2float(bcblk[i]);
  __syncthreads();
  const float* rp = rpl + w * CHUNK * 16;
  float a[8];
#pragma unroll
  for (int n = 0; n < 8; ++n) a[n] = -__expf(alog[((size_t)dir * 64 + d) * 8 + n]);
  const float a0 = a[0];
  bool pw = true;
#pragma unroll
  for (int n = 0; n < 8; ++n) {
    float tgt = (float)(n + 1) * a0;
    pw = pw && (fabsf(a[n] - tgt) <= 1e-3f * fabsf(tgt));
  }
  const float Dv = dsk[dir * 64 + d];
  const __half* up  = xd_in + (size_t)slot * HSLOT_XD + ((size_t)b * L_TOT + ch * CHUNK) * 64;
  const __half* dtp = dtb_base + (size_t)slot * HSLOT_DT + ((size_t)b * L_TOT + ch * CHUNK) * 64;
  float h[8];
  {
    H8pack pk;
    pk.f4 = *(const float4*)(hcb + (size_t)slot * SLOT_HC +
                             (((size_t)b * NCH + ch) * 64 + d) * 8);
#pragma unroll
    for (int k = 0; k < 4; ++k) {
      h[2 * k] = __low2float(pk.h2[k]);
      h[2 * k + 1] = __high2float(pk.h2[k]);
    }
  }
  const int sbase = ch * CHUNK;
  if (pw) {
#pragma unroll 8
    for (int s = 0; s < CHUNK; ++s) {
      float u = __half2float(up[s * 64 + d]);
      float dt = __half2float(dtp[s * 64 + d]);
      float4 b0 = *(const float4*)(rp + s * 16);
      float4 b1 = *(const float4*)(rp + s * 16 + 4);
      float4 c0 = *(const float4*)(rp + s * 16 + 8);
      float4 c1 = *(const float4*)(rp + s * 16 + 12);
      float du = dt * u;
      float p = __expf(dt * a0);
      float p2 = p * p, p3 = p2 * p, p4 = p2 * p2;
      float p5 = p4 * p, p6 = p4 * p2, p7 = p4 * p3, p8 = p4 * p4;
      h[0] = fmaf(p,  h[0], du * b0.x);
      h[1] = fmaf(p2, h[1], du * b0.y);
      h[2] = fmaf(p3, h[2], du * b0.z);
      h[3] = fmaf(p4, h[3], du * b0.w);
      h[4] = fmaf(p5, h[4], du * b1.x);
      h[5] = fmaf(p6, h[5], du * b1.y);
      h[6] = fmaf(p7, h[6], du * b1.z);
      h[7] = fmaf(p8, h[7], du * b1.w);
      float y = u * Dv;
      y = fmaf(c0.x, h[0], y); y = fmaf(c0.y, h[1], y);
      y = fmaf(c0.z, h[2], y); y = fmaf(c0.w, h[3], y);
      y = fmaf(c1.x, h[4], y); y = fmaf(c1.y, h[5], y);
      y = fmaf(c1.z, h[6], y); y = fmaf(c1.w, h[7], y);
      if (scatter) {
        int l = tau_map(dir, sbase + s);
        ysum_f[((size_t)b * L_TOT + l) * 64 + d] += y;
      } else {
        y_h[(size_t)slot * HSLOT_XD + ((size_t)b * L_TOT + sbase + s) * 64 + d] = __float2half(y);
      }
    }
  } else {
#pragma unroll 8
    for (int s = 0; s < CHUNK; ++s) {
      float u = __half2float(up[s * 64 + d]);
      float dt = __half2float(dtp[s * 64 + d]);
      float4 b0 = *(const float4*)(rp + s * 16);
      float4 b1 = *(const float4*)(rp + s * 16 + 4);
      float4 c0 = *(const float4*)(rp + s * 16 + 8);
      float4 c1 = *(const float4*)(rp + s * 16 + 12);
      float du = dt * u;
      float y = u * Dv;
      float bv[8] = {b0.x, b0.y, b0.z, b0.w, b1.x, b1.y, b1.z, b1.w};
      float cv[8] = {c0.x, c0.y, c0.z, c0.w, c1.x, c1.y, c1.z, c1.w};
#pragma unroll
      for (int n = 0; n < 8; ++n) {
        h[n] = fmaf(__expf(dt * a[n]), h[n], du * bv[n]);
        y = fmaf(cv[n], h[n], y);
      }
      if (scatter) {
        int l = tau_map(dir, sbase + s);
        ysum_f[((size_t)b * L_TOT + l) * 64 + d] += y;
      } else {
        y_h[(size_t)slot * HSLOT_XD + ((size_t)b * L_TOT + sbase + s) * 64 + d] = __float2half(y);
      }
    }
  }
}

// ---- F: gather + /4 + LN + *silu(z) + out_proj + residual as LDS-tiled GEMM ----
__global__ void __launch_bounds__(256)
k_final(const __half* __restrict__ yh, const float* __restrict__ ysum,
        const float* __restrict__ zbuf,
        const float* __restrict__ ong, const float* __restrict__ onb,
        const float* __restrict__ OW, const float* __restrict__ inp,
        float* __restrict__ out, int gather) {
  __shared__ float xt[64 * 65];
  __shared__ float tzw[64 * 65];
  __shared__ float st[640];
  const int t = threadIdx.x;
  const int lane = t & 63;
  const int w = t >> 6;
  const int b = blockIdx.x >> 8;
  const int l0 = (blockIdx.x & 255) << 6;
#pragma unroll 2
  for (int rep = 0; rep < 16; ++rep) {
    int r = rep * 4 + w;
    int l = l0 + r;
    float acc;
    if (gather) {
      acc = 0.f;
#pragma unroll
      for (int dir = 0; dir < 4; ++dir) {
        int s = tau_map(dir, l);
        acc += __half2float(yh[(size_t)dir * HSLOT_XD + ((size_t)b * L_TOT + s) * 64 + lane]);
      }
    } else {
      acc = ysum[((size_t)b * L_TOT + l) * 64 + lane];
    }
    xt[r * 65 + lane] = acc * 0.25f;
    tzw[r * 65 + lane] = zbuf[((size_t)b * L_TOT + l) * 64 + lane];
  }
  __syncthreads();
  {
    float s1 = 0.f, s2 = 0.f;
    const int c0 = w * 16;
#pragma unroll
    for (int cc = 0; cc < 16; ++cc) {
      float v = xt[lane * 65 + c0 + cc];
      s1 += v; s2 = fmaf(v, v, s2);
    }
    st[w * 64 + lane] = s1;
    st[256 + w * 64 + lane] = s2;
  }
  __syncthreads();
  if (t < 64) {
    float s1 = st[t] + st[64 + t] + st[128 + t] + st[192 + t];
    float s2 = st[256 + t] + st[320 + t] + st[384 + t] + st[448 + t];
    float m = s1 * 0.015625f;
    float var = s2 * 0.015625f - m * m;
    st[512 + t] = m;
    st[576 + t] = rsqrtf(var + 1e-5f);
  }
  __syncthreads();
  {
    const float mv = st[512 + lane], rv = st[576 + lane];
#pragma unroll 4
    for (int k = 0; k < 16; ++k) {
      int c = w + 4 * k;
      float g = ong[c], bb = onb[c];
      float v = xt[lane * 65 + c];
      float zz = tzw[lane * 65 + c];
      xt[lane * 65 + c] = ((v - mv) * rv * g + bb) * silu_f(zz);
    }
  }
  __syncthreads();
#pragma unroll 4
  for (int rep = 0; rep < 16; ++rep) {
    int j = rep * 4 + w;
    tzw[j * 65 + lane] = OW[(size_t)j * 64 + lane];
  }
  __syncthreads();
  const int rg = lane & 15;
  const int jg = lane >> 4;
  const int j0 = w * 16 + jg * 4;
  const int r0 = rg * 4;
  float acc[4][4] = {};
#pragma unroll 2
  for (int c = 0; c < 64; ++c) {
    float xv[4], wv[4];
#pragma unroll
    for (int i = 0; i < 4; ++i) xv[i] = xt[(r0 + i) * 65 + c];
#pragma unroll
    for (int jj = 0; jj < 4; ++jj) wv[jj] = tzw[(j0 + jj) * 65 + c];
#pragma unroll
    for (int i = 0; i < 4; ++i)
#pragma unroll
      for (int jj = 0; jj < 4; ++jj) acc[i][jj] = fmaf(xv[i], wv[jj], acc[i][jj]);
  }
  __syncthreads();
#pragma unroll
  for (int i = 0; i < 4; ++i)
#pragma unroll
    for (int jj = 0; jj < 4; ++jj) xt[(j0 + jj) * 65 + r0 + i] = acc[i][jj];
  __syncthreads();
#pragma unroll 4
  for (int rep = 0; rep < 16; ++rep) {
    int j = rep * 4 + w;
    size_t o = ((size_t)b * 64 + j) * L_TOT + l0 + lane;
    out[o] = xt[j * 65 + lane] + inp[o];
  }
}

extern "C" void kernel_launch(void* const* d_in, const int* in_sizes, int n_in,
                              void* d_out, int out_size, void* d_ws, size_t ws_size,
                              hipStream_t stream) {
  const float* inp    = (const float*)d_in[0];
  const float* lng    = (const float*)d_in[1];
  const float* lnb    = (const float*)d_in[2];
  const float* ipw    = (const float*)d_in[3];
  const float* cw     = (const float*)d_in[4];
  const float* cb     = (const float*)d_in[5];
  const float* xpw    = (const float*)d_in[6];
  const float* dtw    = (const float*)d_in[7];
  const float* dtbias = (const float*)d_in[8];
  const float* alog   = (const float*)d_in[9];
  const float* dsk    = (const float*)d_in[10];
  const float* ong    = (const float*)d_in[11];
  const float* onb    = (const float*)d_in[12];
  const float* opw    = (const float*)d_in[13];
  float* out = (float*)d_out;
  float* ws = (float*)d_ws;

  // fp32: xbuf, zbuf; fp16: 4x{xd, bc, dt, sdt, hc}.  Total ~59.2 MB (< proven 65.5).
  const size_t half_elems = 4 * (HSLOT_XD + HSLOT_BC + HSLOT_DT + SLOT_SDT + SLOT_HC);
  const size_t need_batched = 2 * SLOT_XD * sizeof(float) + half_elems * sizeof(__half);

  if (ws_size >= need_batched) {
    size_t off = 0;
    float* xbuf = ws + off; off += SLOT_XD;
    float* zbuf = ws + off; off += SLOT_XD;
    __half* hb = (__half*)(ws + off);
    size_t ho = 0;
    __half* xd  = hb + ho; ho += 4 * HSLOT_XD;
    __half* bc  = hb + ho; ho += 4 * HSLOT_BC;
    __half* dtb = hb + ho; ho += 4 * HSLOT_DT;
    __half* sdt = hb + ho; ho += 4 * SLOT_SDT;
    __half* hc  = hb + ho; ho += 4 * SLOT_HC;

    k_ln_inproj<<<dim3(512), 256, 0, stream>>>(inp, lng, lnb, ipw, xbuf, zbuf);
    k_convscan<<<dim3(512, 4), 256, 0, stream>>>(xbuf, cw, cb, xpw, dtw, dtbias, alog,
                                                 xd, bc, dtb, hc, sdt, 0);
    k_scan2<<<dim3(512, 4, B_SZ), NCH, 0, stream>>>(hc, sdt, alog, 0);
    k_scan3<<<dim3(NCH / 4, 4, B_SZ), 256, 0, stream>>>(xd, bc, dtb, hc, alog, dsk,
                                                        nullptr, xd, 0, 0);
    k_final<<<dim3(512), 256, 0, stream>>>(xd, nullptr, zbuf, ong, onb, opw, inp, out, 1);
  } else {
    size_t off = 0;
    float* xbuf = ws + off; off += SLOT_XD;
    float* zbuf = ws + off; off += SLOT_XD;
    float* ysum = ws + off; off += SLOT_XD;
    __half* hb = (__half*)(ws + off);
    size_t ho = 0;
    __half* xd  = hb + ho; ho += HSLOT_XD;
    __half* bc  = hb + ho; ho += HSLOT_BC;
    __half* dtb = hb + ho; ho += HSLOT_DT;
    __half* sdt = hb + ho; ho += SLOT_SDT;
    __half* hc  = hb + ho; ho += SLOT_HC;

    hipMemsetAsync(ysum, 0, SLOT_XD * sizeof(float), stream);
    k_ln_inproj<<<dim3(512), 256, 0, stream>>>(inp, lng, lnb, ipw, xbuf, zbuf);
    for (int d2 = 0; d2 < 4; ++d2) {
      k_convscan<<<dim3(512, 1), 256, 0, stream>>>(xbuf, cw, cb, xpw, dtw, dtbias, alog,
                                                   xd, bc, dtb, hc, sdt, d2);
      k_scan2<<<dim3(512, 1, B_SZ), NCH, 0, stream>>>(hc, sdt, alog, d2);
      k_scan3<<<dim3(NCH / 4, 1, B_SZ), 256, 0, stream>>>(xd, bc, dtb, hc, alog, dsk,
                                                          ysum, nullptr, d2, 1);
    }
    k_final<<<dim3(512), 256, 0, stream>>>(nullptr, ysum, zbuf, ong, onb, opw, inp, out, 0);
  }
}